// Round 10
// baseline (245.539 us; speedup 1.0000x reference)
//
#include <hip/hip_runtime.h>
#include <hip/hip_bf16.h>

#define NV 16384
#define DD 128

typedef __attribute__((ext_vector_type(8))) short bf16x8;
typedef __attribute__((ext_vector_type(8))) unsigned short ushort8v;
typedef __attribute__((ext_vector_type(4))) float f32x4;
typedef __attribute__((ext_vector_type(2))) int i32x2;
typedef long long i64;

#define ASCALE 16384.0f
#define INV_ASCALE (1.0f / 16384.0f)

__device__ __forceinline__ unsigned short f2bf(float x) {
  unsigned u = __builtin_bit_cast(unsigned, x);
  u = (u + 0x7FFFu + ((u >> 16) & 1u)) >> 16;   // round-to-nearest-even
  return (unsigned short)u;
}

__device__ __forceinline__ i64 pk8(f32x4 a, f32x4 b, float s) {
  int lo = 0, hi = 0;
  lo = __builtin_amdgcn_cvt_pk_fp8_f32(a[0] * s, a[1] * s, lo, false);
  lo = __builtin_amdgcn_cvt_pk_fp8_f32(a[2] * s, a[3] * s, lo, true);
  hi = __builtin_amdgcn_cvt_pk_fp8_f32(b[0] * s, b[1] * s, hi, false);
  hi = __builtin_amdgcn_cvt_pk_fp8_f32(b[2] * s, b[3] * s, hi, true);
  i32x2 r; r[0] = lo; r[1] = hi;
  return __builtin_bit_cast(i64, r);
}

// ---------------------------------------------------------------------------
// Kernel 1 (unchanged from round 9): MFMA dual-GEMM for ra (f32) + t (fp8).
// ---------------------------------------------------------------------------
__global__ __launch_bounds__(256) void k_small(
    const float* __restrict__ h, const long long* __restrict__ ridx,
    const float* __restrict__ W, const float* __restrict__ LW,
    const float* __restrict__ RP, const float* __restrict__ bias,
    float* __restrict__ ws_ra, i32x2* __restrict__ tT8)
{
  __shared__ unsigned short rw [64 * 128];    // 16 KB rwh bf16, swizzled
  __shared__ unsigned short Wts[128 * 128];   // 32 KB W^T bf16, swizzled
  __shared__ unsigned short LWts[128 * 128];  // 32 KB LW^T bf16, swizzled
  const int tid = threadIdx.x;
  const int r0  = blockIdx.x * 64;

  {
    const int k  = tid >> 1;            // 0..127
    const int j0 = (tid & 1) * 64;      // j half
    const float* wr  = W  + k * DD + j0;
    const float* lwr = LW + k * DD + j0;
#pragma unroll 8
    for (int i = 0; i < 64; ++i) {
      const int j = j0 + i;
      const int off = j * 128 + (((k >> 3) ^ (j & 7)) << 3) + (k & 7);
      Wts [off] = f2bf(wr[i]);
      LWts[off] = f2bf(lwr[i]);
    }
  }

  {
    const int r  = tid >> 2;            // 0..63
    const int cc = tid & 3;             // 32-col chunk-quad
    const int v  = r0 + r;
    const int reg = ((int)ridx[v]) & 63;
    const float* hp = h  + (size_t)v * DD + cc * 32;
    const float* rp = RP + reg * DD + cc * 32;
#pragma unroll
    for (int i = 0; i < 4; ++i) {
      const f32x4 a  = *(const f32x4*)(hp + i * 8);
      const f32x4 b  = *(const f32x4*)(hp + i * 8 + 4);
      const f32x4 pa = *(const f32x4*)(rp + i * 8);
      const f32x4 pb = *(const f32x4*)(rp + i * 8 + 4);
      ushort8v pk;
#pragma unroll
      for (int q = 0; q < 4; ++q) {
        pk[q]     = f2bf(a[q] * pa[q]);
        pk[4 + q] = f2bf(b[q] * pb[q]);
      }
      const int sc = (cc * 4 + i) ^ (r & 7);
      *(ushort8v*)&rw[r * 128 + sc * 8] = pk;
    }
  }
  __syncthreads();

  const int w = tid >> 6, lane = tid & 63, g = lane >> 4, l15 = lane & 15;
  f32x4 accA[8], accT[8];
#pragma unroll
  for (int f = 0; f < 8; ++f) {
    accA[f] = (f32x4){0.f, 0.f, 0.f, 0.f};
    accT[f] = (f32x4){0.f, 0.f, 0.f, 0.f};
  }
  const int arow = w * 16 + l15;
#pragma unroll
  for (int s = 0; s < 4; ++s) {
    const int sca = (s * 4 + g) ^ (l15 & 7);
    const bf16x8 af = *(const bf16x8*)&rw[arow * 128 + sca * 8];
#pragma unroll
    for (int f = 0; f < 8; ++f) {
      const int j = f * 16 + l15;
      const int scb = (s * 4 + g) ^ (l15 & 7);
      const bf16x8 bw = *(const bf16x8*)&Wts [j * 128 + scb * 8];
      accA[f] = __builtin_amdgcn_mfma_f32_16x16x32_bf16(af, bw, accA[f], 0, 0, 0);
      const bf16x8 bl = *(const bf16x8*)&LWts[j * 128 + scb * 8];
      accT[f] = __builtin_amdgcn_mfma_f32_16x16x32_bf16(af, bl, accT[f], 0, 0, 0);
    }
  }

#pragma unroll
  for (int f = 0; f < 8; ++f) {
    const int col = f * 16 + l15;
    const float bj = bias[col];
#pragma unroll
    for (int q = 0; q < 4; ++q) {
      const int v = r0 + w * 16 + g * 4 + q;
      ws_ra[(size_t)v * DD + col] = accA[f][q] + bj;
    }
  }
#pragma unroll
  for (int f = 0; f < 8; ++f) {
    const int j = f * 16 + l15;
    int own = 0;
    own = __builtin_amdgcn_cvt_pk_fp8_f32(accT[f][0], accT[f][1], own, false);
    own = __builtin_amdgcn_cvt_pk_fp8_f32(accT[f][2], accT[f][3], own, true);
    const int partner = __shfl_xor(own, 16, 64);
    if ((g & 1) == 0) {
      const int v0 = r0 + w * 16 + g * 4;      // multiple of 8
      i32x2 val; val[0] = own; val[1] = partner;
      tT8[(v0 >> 6) * 1024 + ((v0 >> 3) & 7) * 128 + j] = val;
    }
  }
}

// ---------------------------------------------------------------------------
// Kernel 2: partial rb = adj[rows, kquarter] @ t[kquarter].  BM=64, BK=64.
// Split-K x4 (1024 blocks = 4 blocks/CU = 16 waves/CU, launch_bounds(256,4),
// 32KB LDS/block): doubles barrier-group + stream diversity vs round 8.
// K-rotation t0=mblk&63 (channel spread, confirmed R8) + XCD partition
// (2 XCDs per kquarter; B quarter = 0.5MB, L2-resident).
// Depth-3 A/B prefetch: 3 rotating A reg sets (t mod 3), 4 LDS bufs,
// 6 VMEM ops/tile, steady vmcnt(12), tail 12/12/6/0.  64 iters.
// ---------------------------------------------------------------------------
__global__ __launch_bounds__(256, 4) void k_big(
    const float* __restrict__ adj, const unsigned char* __restrict__ tTb,
    float* __restrict__ part)
{
  __shared__ unsigned char Bs[4][8192] __attribute__((aligned(16)));
  const int tid  = threadIdx.x;
  const int w    = tid >> 6;
  const int lane = tid & 63;
  const int g    = lane >> 4;
  const int l15  = lane & 15;
  const int hb   = blockIdx.x;
  const int kh   = (hb & 7) >> 1;             // 0..3: XCD pair per k-quarter
  const int mblk = (hb >> 3) * 2 + (hb & 1);  // 0..255, bijective (1024%8==0)
  const int bid  = mblk * 4 + kh;             // part-buffer slot
  const int r0   = mblk * 64;
  const int t0   = mblk & 63;                 // K-rotation start tile
  const int arow = r0 + w * 16 + l15;
  const float* abase = adj + (size_t)arow * NV + kh * (NV / 4) + g * 8;
  const unsigned char* bbase = tTb + (size_t)kh * 64 * 8192;

#define RT(t) ((t0 + (t)) & 63)

  f32x4 acc[8];
#pragma unroll
  for (int f = 0; f < 8; ++f) acc[f] = (f32x4){0.f, 0.f, 0.f, 0.f};

  f32x4 A0[4], A1[4], A2[4];   // 3 rotating A sets (t mod 3)

#define STAGE(slot, rt) do {                                                   \
    const int buf_ = (slot) & 3;                                               \
    _Pragma("unroll")                                                          \
    for (int i_ = 0; i_ < 2; ++i_) {                                           \
      const int unit_ = i_ * 4 + w;            /* 0..7, wave-uniform */        \
      const unsigned char* src_ = bbase + (size_t)(rt) * 8192 +                \
                                  unit_ * 1024 + lane * 16;                    \
      __builtin_amdgcn_global_load_lds(                                        \
          (const __attribute__((address_space(1))) unsigned int*)src_,         \
          (__attribute__((address_space(3))) unsigned int*)&Bs[buf_][unit_ * 1024], \
          16, 0, 0);                                                           \
    } } while (0)

#define LOADA(AS, rt) do {                                                     \
    const f32x4* p_ = (const f32x4*)(abase + (size_t)(rt) * 64);               \
    AS[0] = p_[0];                                                             \
    AS[1] = p_[1];                                                             \
    const f32x4* q_ = (const f32x4*)(abase + (size_t)(rt) * 64 + 32);          \
    AS[2] = q_[0];                                                             \
    AS[3] = q_[1];                                                             \
  } while (0)

#define COMP(AS, slot) do {                                                    \
    const int buf_ = (slot) & 3;                                               \
    const i64 a0_ = pk8(AS[0], AS[1], ASCALE);                                 \
    const i64 a1_ = pk8(AS[2], AS[3], ASCALE);                                 \
    _Pragma("unroll")                                                          \
    for (int f_ = 0; f_ < 8; ++f_) {                                           \
      const int jr8_ = (f_ * 16 + l15) * 8;                                    \
      acc[f_] = __builtin_amdgcn_mfma_f32_16x16x32_fp8_fp8(a0_,                \
          *(const i64*)&Bs[buf_][g * 1024 + jr8_],       acc[f_], 0, 0, 0);    \
      acc[f_] = __builtin_amdgcn_mfma_f32_16x16x32_fp8_fp8(a1_,                \
          *(const i64*)&Bs[buf_][(4 + g) * 1024 + jr8_], acc[f_], 0, 0, 0);    \
    } } while (0)

#define VW12 asm volatile("s_waitcnt vmcnt(12)" ::: "memory")
#define VW6  asm volatile("s_waitcnt vmcnt(6)"  ::: "memory")
#define VW0  asm volatile("s_waitcnt vmcnt(0)"  ::: "memory")
#define BAR  __builtin_amdgcn_s_barrier()

  // prologue: tiles 0,1,2 in flight (6 ops each, tile-contiguous)
  STAGE(0, RT(0)); LOADA(A0, RT(0));
  STAGE(1, RT(1)); LOADA(A1, RT(1));
  STAGE(2, RT(2)); LOADA(A2, RT(2));

  // steady: iters 0..59 in triples (A-set = t mod 3; stage depth 3)
  for (int tq = 0; tq < 20; ++tq) {
    const int t = tq * 3;
    VW12; BAR; STAGE(t + 3, RT(t + 3)); COMP(A0, t);     LOADA(A0, RT(t + 3));
    VW12; BAR; STAGE(t + 4, RT(t + 4)); COMP(A1, t + 1); LOADA(A1, RT(t + 4));
    VW12; BAR; STAGE(t + 5, RT(t + 5)); COMP(A2, t + 2); LOADA(A2, RT(t + 5));
  }
  // tail: iters 60..63 (60%3==0 -> A0; 63%3==0 -> A0 again)
  VW12; BAR; STAGE(63, RT(63)); COMP(A0, 60); LOADA(A0, RT(63));
  VW12; BAR; COMP(A1, 61);
  VW6;  BAR; COMP(A2, 62);
  VW0;  BAR; COMP(A0, 63);

#undef STAGE
#undef LOADA
#undef COMP
#undef VW12
#undef VW6
#undef VW0
#undef BAR
#undef RT

  // partial write: part[bid][64][128], row=g*4+q, col=f*16+l15 (C/D layout)
  float* pbase = part + ((size_t)bid * 64 + w * 16) * DD;
#pragma unroll
  for (int f = 0; f < 8; ++f) {
    const int col = f * 16 + l15;
#pragma unroll
    for (int q = 0; q < 4; ++q) {
      const int row = g * 4 + q;
      pbase[row * DD + col] = acc[f][q];
    }
  }
}

// ---------------------------------------------------------------------------
// Kernel 3: out = (p0+p1+p2+p3) * 2^-14 + ws_ra  (fixed-order, deterministic)
// ---------------------------------------------------------------------------
__global__ __launch_bounds__(256) void k_reduce(
    const float* __restrict__ part, const float* __restrict__ ws_ra,
    float* __restrict__ out)
{
  const size_t e = ((size_t)blockIdx.x * 256 + threadIdx.x) * 4;
  const int    mblk  = (int)(e >> 13);
  const int    local = (int)(e & 8191);
  const f32x4 p0 = *(const f32x4*)&part[(size_t)(4 * mblk)     * 8192 + local];
  const f32x4 p1 = *(const f32x4*)&part[(size_t)(4 * mblk + 1) * 8192 + local];
  const f32x4 p2 = *(const f32x4*)&part[(size_t)(4 * mblk + 2) * 8192 + local];
  const f32x4 p3 = *(const f32x4*)&part[(size_t)(4 * mblk + 3) * 8192 + local];
  const f32x4 ra = *(const f32x4*)&ws_ra[e];
  f32x4 o;
#pragma unroll
  for (int i = 0; i < 4; ++i)
    o[i] = (((p0[i] + p1[i]) + p2[i]) + p3[i]) * INV_ASCALE + ra[i];
  *(f32x4*)&out[e] = o;
}

extern "C" void kernel_launch(void* const* d_in, const int* in_sizes, int n_in,
                              void* d_out, int out_size, void* d_ws, size_t ws_size,
                              hipStream_t stream) {
  const float*     h    = (const float*)d_in[0];
  const float*     adj  = (const float*)d_in[1];
  const long long* ridx = (const long long*)d_in[2];   // int64 per reference
  const float*     W    = (const float*)d_in[3];
  const float*     LW   = (const float*)d_in[4];
  const float*     RP   = (const float*)d_in[5];
  const float*     bias = (const float*)d_in[6];
  float* out = (float*)d_out;

  float* ws_ra = (float*)d_ws;                                    // 8 MB @ 0
  void*  tT8   = (void*)((char*)d_ws + (size_t)8  * 1024 * 1024); // 2 MB @ 8M
  float* part  = (float*)((char*)d_ws + (size_t)16 * 1024 * 1024);// 32 MB @ 16M

  hipLaunchKernelGGL(k_small, dim3(NV / 64), dim3(256), 0, stream,
                     h, ridx, W, LW, RP, bias, ws_ra, (i32x2*)tT8);
  hipLaunchKernelGGL(k_big, dim3(NV / 64 * 4), dim3(256), 0, stream,
                     adj, (const unsigned char*)tT8, part);
  hipLaunchKernelGGL(k_reduce, dim3((NV * DD / 4) / 256), dim3(256), 0, stream,
                     part, ws_ra, out);
}

// Round 11
// 218.871 us; speedup vs baseline: 1.1218x; 1.1218x over previous
//
#include <hip/hip_runtime.h>
#include <hip/hip_bf16.h>

#define NV 16384
#define DD 128

typedef __attribute__((ext_vector_type(8))) short bf16x8;
typedef __attribute__((ext_vector_type(8))) unsigned short ushort8v;
typedef __attribute__((ext_vector_type(4))) float f32x4;
typedef __attribute__((ext_vector_type(2))) int i32x2;
typedef long long i64;

#define ASCALE 16384.0f
#define INV_ASCALE (1.0f / 16384.0f)

__device__ __forceinline__ unsigned short f2bf(float x) {
  unsigned u = __builtin_bit_cast(unsigned, x);
  u = (u + 0x7FFFu + ((u >> 16) & 1u)) >> 16;   // round-to-nearest-even
  return (unsigned short)u;
}

__device__ __forceinline__ i64 pk8(f32x4 a, f32x4 b, float s) {
  int lo = 0, hi = 0;
  lo = __builtin_amdgcn_cvt_pk_fp8_f32(a[0] * s, a[1] * s, lo, false);
  lo = __builtin_amdgcn_cvt_pk_fp8_f32(a[2] * s, a[3] * s, lo, true);
  hi = __builtin_amdgcn_cvt_pk_fp8_f32(b[0] * s, b[1] * s, hi, false);
  hi = __builtin_amdgcn_cvt_pk_fp8_f32(b[2] * s, b[3] * s, hi, true);
  i32x2 r; r[0] = lo; r[1] = hi;
  return __builtin_bit_cast(i64, r);
}

// ---------------------------------------------------------------------------
// Kernel 1 (unchanged from round 9): MFMA dual-GEMM for ra (f32) + t (fp8).
// ---------------------------------------------------------------------------
__global__ __launch_bounds__(256) void k_small(
    const float* __restrict__ h, const long long* __restrict__ ridx,
    const float* __restrict__ W, const float* __restrict__ LW,
    const float* __restrict__ RP, const float* __restrict__ bias,
    float* __restrict__ ws_ra, i32x2* __restrict__ tT8)
{
  __shared__ unsigned short rw [64 * 128];    // 16 KB rwh bf16, swizzled
  __shared__ unsigned short Wts[128 * 128];   // 32 KB W^T bf16, swizzled
  __shared__ unsigned short LWts[128 * 128];  // 32 KB LW^T bf16, swizzled
  const int tid = threadIdx.x;
  const int r0  = blockIdx.x * 64;

  {
    const int k  = tid >> 1;            // 0..127
    const int j0 = (tid & 1) * 64;      // j half
    const float* wr  = W  + k * DD + j0;
    const float* lwr = LW + k * DD + j0;
#pragma unroll 8
    for (int i = 0; i < 64; ++i) {
      const int j = j0 + i;
      const int off = j * 128 + (((k >> 3) ^ (j & 7)) << 3) + (k & 7);
      Wts [off] = f2bf(wr[i]);
      LWts[off] = f2bf(lwr[i]);
    }
  }

  {
    const int r  = tid >> 2;            // 0..63
    const int cc = tid & 3;             // 32-col chunk-quad
    const int v  = r0 + r;
    const int reg = ((int)ridx[v]) & 63;
    const float* hp = h  + (size_t)v * DD + cc * 32;
    const float* rp = RP + reg * DD + cc * 32;
#pragma unroll
    for (int i = 0; i < 4; ++i) {
      const f32x4 a  = *(const f32x4*)(hp + i * 8);
      const f32x4 b  = *(const f32x4*)(hp + i * 8 + 4);
      const f32x4 pa = *(const f32x4*)(rp + i * 8);
      const f32x4 pb = *(const f32x4*)(rp + i * 8 + 4);
      ushort8v pk;
#pragma unroll
      for (int q = 0; q < 4; ++q) {
        pk[q]     = f2bf(a[q] * pa[q]);
        pk[4 + q] = f2bf(b[q] * pb[q]);
      }
      const int sc = (cc * 4 + i) ^ (r & 7);
      *(ushort8v*)&rw[r * 128 + sc * 8] = pk;
    }
  }
  __syncthreads();

  const int w = tid >> 6, lane = tid & 63, g = lane >> 4, l15 = lane & 15;
  f32x4 accA[8], accT[8];
#pragma unroll
  for (int f = 0; f < 8; ++f) {
    accA[f] = (f32x4){0.f, 0.f, 0.f, 0.f};
    accT[f] = (f32x4){0.f, 0.f, 0.f, 0.f};
  }
  const int arow = w * 16 + l15;
#pragma unroll
  for (int s = 0; s < 4; ++s) {
    const int sca = (s * 4 + g) ^ (l15 & 7);
    const bf16x8 af = *(const bf16x8*)&rw[arow * 128 + sca * 8];
#pragma unroll
    for (int f = 0; f < 8; ++f) {
      const int j = f * 16 + l15;
      const int scb = (s * 4 + g) ^ (l15 & 7);
      const bf16x8 bw = *(const bf16x8*)&Wts [j * 128 + scb * 8];
      accA[f] = __builtin_amdgcn_mfma_f32_16x16x32_bf16(af, bw, accA[f], 0, 0, 0);
      const bf16x8 bl = *(const bf16x8*)&LWts[j * 128 + scb * 8];
      accT[f] = __builtin_amdgcn_mfma_f32_16x16x32_bf16(af, bl, accT[f], 0, 0, 0);
    }
  }

#pragma unroll
  for (int f = 0; f < 8; ++f) {
    const int col = f * 16 + l15;
    const float bj = bias[col];
#pragma unroll
    for (int q = 0; q < 4; ++q) {
      const int v = r0 + w * 16 + g * 4 + q;
      ws_ra[(size_t)v * DD + col] = accA[f][q] + bj;
    }
  }
#pragma unroll
  for (int f = 0; f < 8; ++f) {
    const int j = f * 16 + l15;
    int own = 0;
    own = __builtin_amdgcn_cvt_pk_fp8_f32(accT[f][0], accT[f][1], own, false);
    own = __builtin_amdgcn_cvt_pk_fp8_f32(accT[f][2], accT[f][3], own, true);
    const int partner = __shfl_xor(own, 16, 64);
    if ((g & 1) == 0) {
      const int v0 = r0 + w * 16 + g * 4;      // multiple of 8
      i32x2 val; val[0] = own; val[1] = partner;
      tT8[(v0 >> 6) * 1024 + ((v0 >> 3) & 7) * 128 + j] = val;
    }
  }
}

// ---------------------------------------------------------------------------
// Kernel 2: partial rb = adj[rows, khalf] @ t[khalf].  BM=64, BK=64, fp8.
// Split-K x2 (512 blocks, 2/CU — R9 best).  NEW: A staged through LDS via
// global_load_lds — each staging instr reads 1KB = 4 full rows x 256B
// contiguous (8 whole 128B lines/instr) instead of 16 scattered half-lines
// (the per-instruction granularity probe).  A-LDS chunk-XOR swizzled via
// pre-swizzled global source (dest linear); fragment ds_read_b128 2-way = free.
// 3 bufs x 24KB (A 16K + B 8K), depth-2, 6 gload_lds/wave/tile, vmcnt(6),
// 1 barrier/iter, 128 iters.  K-rotation t0=mblk&127; XCD kh-partition.
// ---------------------------------------------------------------------------
__global__ __launch_bounds__(256, 2) void k_big(
    const float* __restrict__ adj, const unsigned char* __restrict__ tTb,
    float* __restrict__ part)
{
  __shared__ unsigned char Bs[3][24576] __attribute__((aligned(16)));
  const int tid  = threadIdx.x;
  const int w    = tid >> 6;
  const int lane = tid & 63;
  const int g    = lane >> 4;
  const int l15  = lane & 15;
  const int hb   = blockIdx.x;
  const int kh   = (hb & 7) >> 2;             // XCD partition: bid%8<4 -> kh0
  const int mblk = (hb >> 3) * 4 + (hb & 3);  // bijective remap (512 % 8 == 0)
  const int bid  = mblk * 2 + kh;             // part-buffer slot
  const int r0   = mblk * 64;
  const int t0   = mblk & 127;                // K-rotation over 128 tiles
  const unsigned char* bbase = tTb + (size_t)kh * 128 * 8192;

#define RT(t) ((t0 + (t)) & 127)

  // per-lane pre-swizzled A staging sources (i = 0..3, 4 rows per instr)
  const float* asrc[4];
#pragma unroll
  for (int i = 0; i < 4; ++i) {
    const int rrel = w * 16 + i * 4 + (lane >> 4);        // row within tile
    const int cswz = (lane & 15) ^ ((i * 4 + (lane >> 4)) & 7);
    asrc[i] = adj + (size_t)(r0 + rrel) * NV + kh * (NV / 2) + cswz * 4;
  }

  f32x4 acc[8];
#pragma unroll
  for (int f = 0; f < 8; ++f) acc[f] = (f32x4){0.f, 0.f, 0.f, 0.f};

#define STAGE(bufidx, rt) do {                                                 \
    _Pragma("unroll")                                                          \
    for (int i_ = 0; i_ < 4; ++i_) {   /* A: 4 instrs, 4 rows x 256B each */   \
      const float* srcA_ = asrc[i_] + (size_t)(rt) * 64;                       \
      unsigned char* dstA_ = &Bs[bufidx][(w * 16 + i_ * 4) * 256];             \
      __builtin_amdgcn_global_load_lds(                                        \
          (const __attribute__((address_space(1))) unsigned int*)srcA_,        \
          (__attribute__((address_space(3))) unsigned int*)dstA_, 16, 0, 0);   \
    }                                                                          \
    _Pragma("unroll")                                                          \
    for (int i_ = 0; i_ < 2; ++i_) {   /* B: 2 instrs */                       \
      const int unit_ = i_ * 4 + w;                                            \
      const unsigned char* srcB_ = bbase + (size_t)(rt) * 8192 +               \
                                   unit_ * 1024 + lane * 16;                   \
      unsigned char* dstB_ = &Bs[bufidx][16384 + unit_ * 1024];                \
      __builtin_amdgcn_global_load_lds(                                        \
          (const __attribute__((address_space(1))) unsigned int*)srcB_,        \
          (__attribute__((address_space(3))) unsigned int*)dstB_, 16, 0, 0);   \
    } } while (0)

#define COMP(bufidx) do {                                                      \
    const unsigned char* Ab_ = &Bs[bufidx][(w * 16 + l15) * 256];              \
    const int x_ = l15 & 7;                                                    \
    const f32x4 c0_ = *(const f32x4*)&Ab_[((2 * g)     ^ x_) * 16];            \
    const f32x4 c1_ = *(const f32x4*)&Ab_[((2 * g + 1) ^ x_) * 16];            \
    const f32x4 c2_ = *(const f32x4*)&Ab_[((8 + 2 * g)     ^ x_) * 16];        \
    const f32x4 c3_ = *(const f32x4*)&Ab_[((8 + 2 * g + 1) ^ x_) * 16];        \
    const i64 a0_ = pk8(c0_, c1_, ASCALE);                                     \
    const i64 a1_ = pk8(c2_, c3_, ASCALE);                                     \
    const unsigned char* Bb_ = &Bs[bufidx][16384];                             \
    _Pragma("unroll")                                                          \
    for (int f_ = 0; f_ < 8; ++f_) {                                           \
      const int jr8_ = (f_ * 16 + l15) * 8;                                    \
      acc[f_] = __builtin_amdgcn_mfma_f32_16x16x32_fp8_fp8(a0_,                \
          *(const i64*)&Bb_[g * 1024 + jr8_],       acc[f_], 0, 0, 0);         \
      acc[f_] = __builtin_amdgcn_mfma_f32_16x16x32_fp8_fp8(a1_,                \
          *(const i64*)&Bb_[(4 + g) * 1024 + jr8_], acc[f_], 0, 0, 0);         \
    } } while (0)

#define VW6  asm volatile("s_waitcnt vmcnt(6)" ::: "memory")
#define VW0  asm volatile("s_waitcnt vmcnt(0)" ::: "memory")
#define BAR  __builtin_amdgcn_s_barrier()

  // prologue: tiles 0,1 in flight (6 ops each, tile-contiguous)
  STAGE(0, RT(0));
  STAGE(1, RT(1));

  // steady: iters 0..125 in triples (buf = t % 3), depth-2, vmcnt(6)
  for (int tq = 0; tq < 42; ++tq) {
    const int t = tq * 3;
    VW6; BAR; STAGE(2, RT(t + 2)); COMP(0);
    VW6; BAR; STAGE(0, RT(t + 3)); COMP(1);
    VW6; BAR; STAGE(1, RT(t + 4)); COMP(2);
  }
  // tail: iters 126 (buf 0), 127 (buf 1); loop already staged RT(127)
  VW6; BAR; COMP(0);
  VW0; BAR; COMP(1);

#undef STAGE
#undef COMP
#undef VW6
#undef VW0
#undef BAR
#undef RT

  // partial write: part[bid][64][128], row=g*4+q, col=f*16+l15 (C/D layout)
  float* pbase = part + ((size_t)bid * 64 + w * 16) * DD;
#pragma unroll
  for (int f = 0; f < 8; ++f) {
    const int col = f * 16 + l15;
#pragma unroll
    for (int q = 0; q < 4; ++q) {
      const int row = g * 4 + q;
      pbase[row * DD + col] = acc[f][q];
    }
  }
}

// ---------------------------------------------------------------------------
// Kernel 3: out = (part0 + part1) * 2^-14 + ws_ra   (deterministic reduce)
// ---------------------------------------------------------------------------
__global__ __launch_bounds__(256) void k_reduce(
    const float* __restrict__ part, const float* __restrict__ ws_ra,
    float* __restrict__ out)
{
  const size_t e = ((size_t)blockIdx.x * 256 + threadIdx.x) * 4;
  const int    mblk  = (int)(e >> 13);
  const int    local = (int)(e & 8191);
  const f32x4 p0 = *(const f32x4*)&part[(size_t)(2 * mblk)     * 8192 + local];
  const f32x4 p1 = *(const f32x4*)&part[(size_t)(2 * mblk + 1) * 8192 + local];
  const f32x4 ra = *(const f32x4*)&ws_ra[e];
  f32x4 o;
#pragma unroll
  for (int i = 0; i < 4; ++i) o[i] = (p0[i] + p1[i]) * INV_ASCALE + ra[i];
  *(f32x4*)&out[e] = o;
}

extern "C" void kernel_launch(void* const* d_in, const int* in_sizes, int n_in,
                              void* d_out, int out_size, void* d_ws, size_t ws_size,
                              hipStream_t stream) {
  const float*     h    = (const float*)d_in[0];
  const float*     adj  = (const float*)d_in[1];
  const long long* ridx = (const long long*)d_in[2];   // int64 per reference
  const float*     W    = (const float*)d_in[3];
  const float*     LW   = (const float*)d_in[4];
  const float*     RP   = (const float*)d_in[5];
  const float*     bias = (const float*)d_in[6];
  float* out = (float*)d_out;

  float* ws_ra = (float*)d_ws;                                    // 8 MB @ 0
  void*  tT8   = (void*)((char*)d_ws + (size_t)8  * 1024 * 1024); // 2 MB @ 8M
  float* part  = (float*)((char*)d_ws + (size_t)16 * 1024 * 1024);// 16 MB @ 16M

  hipLaunchKernelGGL(k_small, dim3(NV / 64), dim3(256), 0, stream,
                     h, ridx, W, LW, RP, bias, ws_ra, (i32x2*)tT8);
  hipLaunchKernelGGL(k_big, dim3(NV / 64 * 2), dim3(256), 0, stream,
                     adj, (const unsigned char*)tT8, part);
  hipLaunchKernelGGL(k_reduce, dim3((NV * DD / 4) / 256), dim3(256), 0, stream,
                     part, ws_ra, out);
}